// Round 6
// baseline (174.490 us; speedup 1.0000x reference)
//
#include <hip/hip_runtime.h>
#include <stdint.h>

// YOLOv3 decode. R6: DRAM-granule attack. R1-R5 all plateau at ~1.5 TB/s
// (~1/4 of streaming BW) with scattered <=1 KB granules at 10.8 KB stride;
// hypothesis: DRAM row efficiency ~25%. Here each wave DMAs one channel's
// 4-KB chunk as 4 back-to-back contiguous global_load_lds (1 KB each),
// streaming 85 channels in groups of 8 through double-buffered LDS.
// Block = (b, anchor=grid.y, 1024-cell tile). Scale 13 stays scalar.

#define AS1 __attribute__((address_space(1)))
#define AS3 __attribute__((address_space(3)))

__device__ __forceinline__ void cp16_async(const float* g, float* l) {
    __builtin_amdgcn_global_load_lds((const AS1 void*)(uintptr_t)g,
                                     (AS3 void*)(uint32_t)(uintptr_t)l,
                                     16, 0, 0);
}

// Stage 8 channels x <=1024 cells: wave wv bursts channels g*8+2wv, +1 as
// ni sequential 1-KB instructions each. Per-lane global clamp to slab end.
template<int HW>
__device__ __forceinline__ void dma_group(
    const float* slab, const float* slab_last, int tile0, int ni,
    int g, float* L, int lane, int wv)
{
#pragma unroll
    for (int k = 0; k < 2; ++k) {
        const int s  = 2 * wv + k;
        const int ch = g * 8 + s;
        if (ch < 85) {
            const float* gp0 = slab + (size_t)ch * HW + tile0;
            float* lp0 = L + s * 1024;
            for (int i = 0; i < ni; ++i) {
                const float* gp = gp0 + i * 256 + lane * 4;
                if (gp > slab_last) gp = slab_last;
                cp16_async(gp, lp0 + i * 256);
            }
        }
    }
}

template<int HW, int W>
__device__ __forceinline__ void decode_tile(
    const float* __restrict__ in, const float* __restrict__ anch,
    float scale, float inv_case, float th,
    int b, int a, int tile0, int row_base,
    float* __restrict__ boxes, float* __restrict__ mask, float* smem)
{
    const int tid  = threadIdx.x;
    const int lane = tid & 63;
    const int wv   = tid >> 6;

    const float* slab      = in + ((size_t)b * 255 + (size_t)a * 85) * HW;
    const float* slab_last = slab + (size_t)85 * HW - 4;  // last valid float4

    int nvalid = HW - tile0; if (nvalid > 1024) nvalid = 1024;
    const int ni = (nvalid + 255) >> 8;

    float best[4]; int bi[4]; float o[5][4];
#pragma unroll
    for (int j = 0; j < 4; ++j) { best[j] = -__builtin_inff(); bi[j] = 0; }

    dma_group<HW>(slab, slab_last, tile0, ni, 0, smem, lane, wv);

    // ---- group 0 (peeled: compile-time slots -> box channels in registers)
    __syncthreads();
    dma_group<HW>(slab, slab_last, tile0, ni, 1, smem + 8192, lane, wv);
    {
        const float* L = smem;
#pragma unroll
        for (int s = 0; s < 8; ++s) {
            float4 v = *reinterpret_cast<const float4*>(L + s * 1024 + 4 * tid);
            float vv[4] = {v.x, v.y, v.z, v.w};
            if (s < 5) {
#pragma unroll
                for (int j = 0; j < 4; ++j) o[s][j] = vv[j];
            } else {
#pragma unroll
                for (int j = 0; j < 4; ++j)
                    if (vv[j] > best[j]) { best[j] = vv[j]; bi[j] = s - 5; }
            }
        }
    }
    // ---- groups 1..10 (all class channels)
    for (int g = 1; g < 11; ++g) {
        __syncthreads();
        if (g < 10)
            dma_group<HW>(slab, slab_last, tile0, ni, g + 1,
                          smem + ((g + 1) & 1) * 8192, lane, wv);
        const float* L = smem + (g & 1) * 8192;
        const int nch = (g == 10) ? 5 : 8;
#pragma unroll
        for (int s = 0; s < 8; ++s) {
            if (s < nch) {
                float4 v = *reinterpret_cast<const float4*>(L + s * 1024 + 4 * tid);
                float vv[4] = {v.x, v.y, v.z, v.w};
                int k = g * 8 + s - 5;
#pragma unroll
                for (int j = 0; j < 4; ++j)
                    if (vv[j] > best[j]) { best[j] = vv[j]; bi[j] = k; }
            }
        }
    }

    const float aw = anch[2 * a + 0] * inv_case;
    const float ah = anch[2 * a + 1] * inv_case;
#pragma unroll
    for (int j = 0; j < 4; ++j) {
        int hw = tile0 + 4 * tid + j;
        if (hw < HW) {
            int h = hw / W;
            int w = hw - h * W;
            float px = 1.0f / (1.0f + __expf(-o[0][j]));
            float cx = ((float)w + o[1][j]) * scale;
            float cy = ((float)h + o[2][j]) * scale;
            float bw = aw * __expf(o[3][j]);
            float bh = ah * __expf(o[4][j]);
            int row = row_base + (b * HW + hw) * 3 + a;
            float2* ob = reinterpret_cast<float2*>(boxes + (size_t)row * 6);
            ob[0] = make_float2(px, cx);
            ob[1] = make_float2(cy, bw);
            ob[2] = make_float2(bh, (float)bi[j]);
            mask[row] = (o[0][j] > th) ? 1.0f : 0.0f;
        }
    }
}

// scalar path for 13x13 (4.7% of data) — R3 structure (verified)
__device__ __forceinline__ void decode_scalar13(
    const float* __restrict__ in, const float* __restrict__ anch,
    float scale, float inv_case, float th,
    int a, int cell, float* __restrict__ boxes, float* __restrict__ mask)
{
    constexpr int HW = 169;
    int b  = cell / HW;
    int hw = cell - b * HW;
    int h  = hw / 13;
    int w  = hw - h * 13;

    const float* p = in + ((size_t)b * 255 + (size_t)a * 85) * HW + hw;

    float o0 = p[0 * HW];
    float o1 = p[1 * HW];
    float o2 = p[2 * HW];
    float o3 = p[3 * HW];
    float o4 = p[4 * HW];

    float best = -__builtin_inff();
    int   bi   = 0;
    const float* pc = p + 5 * HW;
#pragma unroll
    for (int g = 0; g < 4; ++g) {
        float v[20];
#pragma unroll
        for (int j = 0; j < 20; ++j) v[j] = pc[(g * 20 + j) * HW];
#pragma unroll
        for (int j = 0; j < 20; ++j)
            if (v[j] > best) { best = v[j]; bi = g * 20 + j; }
    }

    float px = 1.0f / (1.0f + __expf(-o0));
    float cx = ((float)w + o1) * scale;
    float cy = ((float)h + o2) * scale;
    float bw = anch[2 * a + 0] * __expf(o3) * inv_case;
    float bh = anch[2 * a + 1] * __expf(o4) * inv_case;

    int row = cell * 3 + a;
    float2* ob = reinterpret_cast<float2*>(boxes + (size_t)row * 6);
    ob[0] = make_float2(px, cx);
    ob[1] = make_float2(cy, bw);
    ob[2] = make_float2(bh, (float)bi);
    mask[row] = (o0 > th) ? 1.0f : 0.0f;
}

__global__ __launch_bounds__(256) void detector_kernel(
    const float* __restrict__ in13, const float* __restrict__ in26,
    const float* __restrict__ in52,
    const float* __restrict__ a13, const float* __restrict__ a26,
    const float* __restrict__ a52,
    const float* __restrict__ thp, const int* __restrict__ casep,
    float* __restrict__ boxes, float* __restrict__ mask,
    int B, int base26, int base52)
{
    __shared__ float smem[2 * 8 * 1024];   // 64 KB: double-buffered 8-ch group

    const int a  = blockIdx.y;
    const int bx = blockIdx.x;
    const float th       = thp[0];
    const float inv_case = 1.0f / (float)casep[0];

    const int n52x = B * 3;   // (b, tile 0..2)
    const int n26x = B;       // (b), single tile

    if (bx < n52x) {
        int b  = bx / 3;
        int tl = bx - b * 3;
        decode_tile<2704, 52>(in52, a52, 8.0f * inv_case, inv_case, th,
                              b, a, tl * 1024, base52, boxes, mask, smem);
    } else if (bx < n52x + n26x) {
        int b = bx - n52x;
        decode_tile<676, 26>(in26, a26, 16.0f * inv_case, inv_case, th,
                             b, a, 0, base26, boxes, mask, smem);
    } else {
        int t = (bx - n52x - n26x) * 256 + threadIdx.x;
        if (t < B * 169)
            decode_scalar13(in13, a13, 32.0f * inv_case, inv_case, th,
                            a, t, boxes, mask);
    }
}

extern "C" void kernel_launch(void* const* d_in, const int* in_sizes, int n_in,
                              void* d_out, int out_size, void* d_ws, size_t ws_size,
                              hipStream_t stream) {
    const float* in13 = (const float*)d_in[0];
    const float* in26 = (const float*)d_in[1];
    const float* in52 = (const float*)d_in[2];
    const float* a13  = (const float*)d_in[3];
    const float* a26  = (const float*)d_in[4];
    const float* a52  = (const float*)d_in[5];
    const float* thp  = (const float*)d_in[6];
    const int*   casep = (const int*)d_in[7];

    const int B = in_sizes[0] / (255 * 169);

    const int base26 = B * 169 * 3;
    const int base52 = B * (169 + 676) * 3;

    const int n52x = B * 3;
    const int n26x = B;
    const int n13x = (B * 169 + 255) / 256;

    const int nrows = B * (169 + 676 + 2704) * 3;
    float* boxes = (float*)d_out;
    float* mask  = (float*)d_out + (size_t)nrows * 6;

    dim3 grid(n52x + n26x + n13x, 3);
    detector_kernel<<<grid, 256, 0, stream>>>(
        in13, in26, in52, a13, a26, a52, thp, casep,
        boxes, mask, B, base26, base52);
}

// Round 7
// 172.563 us; speedup vs baseline: 1.0112x; 1.0112x over previous
//
#include <hip/hip_runtime.h>

// YOLOv3 decode. R7: non-temporal loads/stores on R5's structure.
// R1-R6: read BW pinned at ~1.5 TB/s across all structural variants.
// Theory: TCC hit/miss/evict interleave (ws-poison fill dirties+evicts L3
// between input restore and kernel) serializes the read path. NT loads
// read through without allocating; NT stores skip RMW allocate.

#define NCLS 80

template<int HW, int W>
__device__ __forceinline__ void decode4(
    const float* __restrict__ in, const float* __restrict__ anch,
    float scale, float inv_case, float th,
    int a, int t, int row_base, int B,
    float* __restrict__ boxes, float* __restrict__ mask)
{
    if (t >= B * HW * 4) return;
    const int rt  = t >> 2;          // row: b*HW + hw
    const int seg = t & 3;           // class segment 0..3
    const int b   = rt / HW;         // compile-time divisor -> magic mul
    const int hw  = rt - b * HW;

    const float* p = in + ((size_t)b * 255 + (size_t)a * 85) * HW + hw;

    // 20 independent non-temporal class loads, then compare.
    const float* pc = p + (size_t)(5 + seg * 20) * HW;
    float v[20];
#pragma unroll
    for (int j = 0; j < 20; ++j)
        v[j] = __builtin_nontemporal_load(pc + (size_t)j * HW);

    float best = v[0];
    int   bi   = seg * 20;
#pragma unroll
    for (int j = 1; j < 20; ++j)
        if (v[j] > best) { best = v[j]; bi = seg * 20 + j; }

    // box channels (all 4 segs read same lines; issue before reduce)
    float o0 = __builtin_nontemporal_load(p + 0 * (size_t)HW);
    float o1 = __builtin_nontemporal_load(p + 1 * (size_t)HW);
    float o2 = __builtin_nontemporal_load(p + 2 * (size_t)HW);
    float o3 = __builtin_nontemporal_load(p + 3 * (size_t)HW);
    float o4 = __builtin_nontemporal_load(p + 4 * (size_t)HW);

    // quad butterfly reduce: max, smallest-index tie-break (jnp.argmax)
#pragma unroll
    for (int m = 1; m <= 2; m <<= 1) {
        float ob = __shfl_xor(best, m);
        int   oi = __shfl_xor(bi,   m);
        if (ob > best || (ob == best && oi < bi)) { best = ob; bi = oi; }
    }

    if (seg == 0) {
        int h = hw / W;
        int w = hw - h * W;
        float px = 1.0f / (1.0f + __expf(-o0));
        float cx = ((float)w + o1) * scale;
        float cy = ((float)h + o2) * scale;
        float bw = anch[2 * a + 0] * __expf(o3) * inv_case;
        float bh = anch[2 * a + 1] * __expf(o4) * inv_case;

        int row = row_base + rt * 3 + a;
        float* ob2 = boxes + (size_t)row * 6;
        __builtin_nontemporal_store(px, ob2 + 0);
        __builtin_nontemporal_store(cx, ob2 + 1);
        __builtin_nontemporal_store(cy, ob2 + 2);
        __builtin_nontemporal_store(bw, ob2 + 3);
        __builtin_nontemporal_store(bh, ob2 + 4);
        __builtin_nontemporal_store((float)bi, ob2 + 5);
        __builtin_nontemporal_store((o0 > th) ? 1.0f : 0.0f, mask + row);
    }
}

__global__ __launch_bounds__(256) void detector_kernel(
    const float* __restrict__ in13, const float* __restrict__ in26,
    const float* __restrict__ in52,
    const float* __restrict__ a13, const float* __restrict__ a26,
    const float* __restrict__ a52,
    const float* __restrict__ thp, const int* __restrict__ casep,
    float* __restrict__ boxes, float* __restrict__ mask,
    int B, int nb52, int nb26)
{
    const int a  = blockIdx.y;
    const int bx = blockIdx.x;
    const float th       = thp[0];
    const float inv_case = 1.0f / (float)casep[0];

    if (bx < nb52) {
        int t = bx * 256 + threadIdx.x;
        decode4<2704, 52>(in52, a52, 8.0f * inv_case, inv_case, th,
                          a, t, B * (169 + 676) * 3, B, boxes, mask);
    } else if (bx < nb52 + nb26) {
        int t = (bx - nb52) * 256 + threadIdx.x;
        decode4<676, 26>(in26, a26, 16.0f * inv_case, inv_case, th,
                         a, t, B * 169 * 3, B, boxes, mask);
    } else {
        int t = (bx - nb52 - nb26) * 256 + threadIdx.x;
        decode4<169, 13>(in13, a13, 32.0f * inv_case, inv_case, th,
                         a, t, 0, B, boxes, mask);
    }
}

extern "C" void kernel_launch(void* const* d_in, const int* in_sizes, int n_in,
                              void* d_out, int out_size, void* d_ws, size_t ws_size,
                              hipStream_t stream) {
    const float* in13 = (const float*)d_in[0];
    const float* in26 = (const float*)d_in[1];
    const float* in52 = (const float*)d_in[2];
    const float* a13  = (const float*)d_in[3];
    const float* a26  = (const float*)d_in[4];
    const float* a52  = (const float*)d_in[5];
    const float* thp  = (const float*)d_in[6];
    const int*   casep = (const int*)d_in[7];

    const int B = in_sizes[0] / (255 * 169);

    const int nb52 = (B * 2704 * 4 + 255) / 256;
    const int nb26 = (B * 676  * 4 + 255) / 256;
    const int nb13 = (B * 169  * 4 + 255) / 256;

    const int nrows = B * (169 + 676 + 2704) * 3;
    float* boxes = (float*)d_out;
    float* mask  = (float*)d_out + (size_t)nrows * 6;

    dim3 grid(nb52 + nb26 + nb13, 3);
    detector_kernel<<<grid, 256, 0, stream>>>(
        in13, in26, in52, a13, a26, a52, thp, casep,
        boxes, mask, B, nb52, nb26);
}